// Round 1
// baseline (1181.190 us; speedup 1.0000x reference)
//
#include <hip/hip_runtime.h>
#include <stdint.h>

#define T_TOK 32768
#define D_DIM 512
#define F_DIM 2048
#define NE    64

typedef __bf16 bf16_t;
typedef __bf16 bf16x8 __attribute__((ext_vector_type(8)));
typedef __bf16 bf16x4 __attribute__((ext_vector_type(4)));
typedef float  f32x4  __attribute__((ext_vector_type(4)));

// ---------- async global->LDS 16B (wave-uniform base + lane*16 rule) ----------
__device__ __forceinline__ void async_copy16(const void* g, void* l) {
  __builtin_amdgcn_global_load_lds(
      (__attribute__((address_space(1))) unsigned int*)g,
      (__attribute__((address_space(3))) unsigned int*)l, 16, 0, 0);
}

// ---------- tiny routing kernels ----------
__global__ void hist_k(const int* __restrict__ e, int* __restrict__ counts) {
  int t = blockIdx.x * 256 + threadIdx.x;
  atomicAdd(&counts[e[t]], 1);
}

__global__ void scan_k(const int* __restrict__ counts, int* __restrict__ offsets) {
  if (threadIdx.x == 0) {
    int acc = 0;
    for (int i = 0; i < NE; ++i) { offsets[i] = acc; acc += counts[i]; }
    offsets[NE] = acc;
  }
}

__global__ void assign_k(const int* __restrict__ e, const int* __restrict__ offsets,
                         int* __restrict__ cursor, int* __restrict__ perm) {
  int t = blockIdx.x * 256 + threadIdx.x;
  int ex = e[t];
  int s = atomicAdd(&cursor[ex], 1);
  perm[offsets[ex] + s] = t;
}

// gather tokens into slot order + fp32->bf16. one block (128 thr) per slot.
__global__ void gather_x_k(const float* __restrict__ x, const int* __restrict__ perm,
                           bf16_t* __restrict__ xg) {
  int s = blockIdx.x;
  int t = perm[s];
  float4 v = ((const float4*)(x + (size_t)t * D_DIM))[threadIdx.x];
  bf16x4 o = { (bf16_t)v.x, (bf16_t)v.y, (bf16_t)v.z, (bf16_t)v.w };
  *(bf16x4*)(xg + (size_t)s * D_DIM + threadIdx.x * 4) = o;
}

// ---------- tiled transpose + convert: in [E][R][C] f32 -> out [E][C][R] bf16 ----------
__global__ void transpose_k(const float* __restrict__ in, bf16_t* __restrict__ out,
                            int R, int C) {
  __shared__ float tile[64][65];
  int e = blockIdx.z;
  int c0 = blockIdx.x * 64, r0 = blockIdx.y * 64;
  const float* inp = in + (size_t)e * R * C;
  bf16_t* outp = out + (size_t)e * C * R;
  int lr = threadIdx.x >> 6;   // 0..3
  int lc = threadIdx.x & 63;   // 0..63
  #pragma unroll
  for (int p = 0; p < 16; ++p) {
    int r = p * 4 + lr;
    tile[r][lc] = inp[(size_t)(r0 + r) * C + c0 + lc];
  }
  __syncthreads();
  #pragma unroll
  for (int p = 0; p < 16; ++p) {
    int cr = p * 4 + lr;
    outp[(size_t)(c0 + cr) * R + r0 + lc] = (bf16_t)tile[lc][cr];
  }
}

// ---------- grouped GEMM: C[m][n] = sum_k A[slot][k] * Bt[e][n][k] ----------
// A slot-major [T][KDIM] bf16; Bt [E][NDIM][KDIM] bf16 (k-contiguous rows).
// IS_G1: epilogue = exact gelu(acc + b1) -> H bf16.  else: acc + b2 -> scatter fp32 out via perm.
template<int KDIM, int NDIM, bool IS_G1>
__global__ __launch_bounds__(256, 2)
void gemm_k(const bf16_t* __restrict__ A, const bf16_t* __restrict__ Bt,
            const float* __restrict__ bias, const int* __restrict__ offsets,
            const int* __restrict__ perm, bf16_t* __restrict__ Hout,
            float* __restrict__ Yout)
{
  const int e = blockIdx.y;
  const int row_base = offsets[e];
  const int ne = offsets[e + 1] - row_base;
  const int mt = blockIdx.x & 7;
  const int nt = blockIdx.x >> 3;
  const int m0 = mt << 7;
  if (m0 >= ne) return;
  const int n0 = nt << 7;
  const int mlen = min(128, ne - m0);

  __shared__ bf16_t As[128 * 64];
  __shared__ bf16_t Bs[128 * 64];

  const int tid = threadIdx.x;
  const int lane = tid & 63;
  const int wave = tid >> 6;
  const int wm = (wave >> 1) << 6;
  const int wn = (wave & 1) << 6;
  const int l15 = lane & 15;
  const int quad = lane >> 4;

  f32x4 acc[4][4] = {};

  const bf16_t* Bexp = Bt + ((size_t)e * NDIM + n0) * KDIM;

  // each thread stages 4 A-chunks + 4 B-chunks (16B each) per K-tile.
  // chunk index c -> LDS row r=c>>3, chunk-in-row cc=c&7; XOR-swizzle: data at
  // physical chunk cc holds logical chunk cc^(r&7).
  const bf16_t* asrc[4];
  const bf16_t* bsrc[4];
  int lchunk[4];
  #pragma unroll
  for (int p = 0; p < 4; ++p) {
    int c = tid + p * 256;
    int r = c >> 3;
    int cc = c & 7;
    int gc = cc ^ (r & 7);
    int garow = row_base + m0 + r;
    garow = garow < T_TOK ? garow : (T_TOK - 1);   // clamp: padded rows read valid mem, never stored
    asrc[p] = A + (size_t)garow * KDIM + gc * 8;
    bsrc[p] = Bexp + (size_t)r * KDIM + gc * 8;
    lchunk[p] = c;
  }

  for (int kt = 0; kt < KDIM / 64; ++kt) {
    __syncthreads();
    const int k0 = kt * 64;
    #pragma unroll
    for (int p = 0; p < 4; ++p) {
      async_copy16(asrc[p] + k0, &As[lchunk[p] * 8]);
      async_copy16(bsrc[p] + k0, &Bs[lchunk[p] * 8]);
    }
    __syncthreads();
    #pragma unroll
    for (int ks = 0; ks < 2; ++ks) {
      bf16x8 af[4], bfr[4];
      #pragma unroll
      for (int i = 0; i < 4; ++i) {
        int ra = wm + i * 16 + l15;
        int pa = ((ks << 2) + quad) ^ (ra & 7);
        af[i] = *(const bf16x8*)&As[ra * 64 + pa * 8];
        int rb = wn + i * 16 + l15;
        int pb = ((ks << 2) + quad) ^ (rb & 7);
        bfr[i] = *(const bf16x8*)&Bs[rb * 64 + pb * 8];
      }
      #pragma unroll
      for (int i = 0; i < 4; ++i)
        #pragma unroll
        for (int j = 0; j < 4; ++j)
          acc[i][j] = __builtin_amdgcn_mfma_f32_16x16x32_bf16(af[i], bfr[j], acc[i][j], 0, 0, 0);
    }
  }

  // epilogue: C/D layout col=lane&15, row=quad*4+reg
  #pragma unroll
  for (int i = 0; i < 4; ++i) {
    #pragma unroll
    for (int rr = 0; rr < 4; ++rr) {
      int m = wm + i * 16 + quad * 4 + rr;
      if (m < mlen) {
        int sg = row_base + m0 + m;
        #pragma unroll
        for (int j = 0; j < 4; ++j) {
          int col = n0 + wn + j * 16 + l15;
          float v = acc[i][j][rr] + bias[e * NDIM + col];
          if (IS_G1) {
            float g = 0.5f * v * (1.0f + erff(v * 0.7071067811865476f));
            Hout[(size_t)sg * F_DIM + col] = (bf16_t)g;
          } else {
            int t = perm[sg];
            Yout[(size_t)t * D_DIM + col] = v;
          }
        }
      }
    }
  }
}

extern "C" void kernel_launch(void* const* d_in, const int* in_sizes, int n_in,
                              void* d_out, int out_size, void* d_ws, size_t ws_size,
                              hipStream_t stream) {
  const float* x   = (const float*)d_in[0];
  const int* disp  = (const int*)d_in[1];
  const float* w1  = (const float*)d_in[2];
  const float* b1  = (const float*)d_in[3];
  const float* w2  = (const float*)d_in[4];
  const float* b2  = (const float*)d_in[5];
  float* out = (float*)d_out;

  char* ws = (char*)d_ws;
  int* counts  = (int*)(ws + 0);      // 64 ints
  int* cursor  = (int*)(ws + 256);    // 64 ints
  int* offsets = (int*)(ws + 512);    // 65 ints
  int* perm    = (int*)(ws + 1024);   // 32768 ints
  bf16_t* Xg  = (bf16_t*)(ws + 132096ULL);      // [T][512] bf16, slot-major
  bf16_t* w1t = (bf16_t*)(ws + 33686528ULL);    // [E][2048][512] bf16
  bf16_t* w2t = (bf16_t*)(ws + 167904256ULL);   // [E][512][2048] bf16
  bf16_t* H   = (bf16_t*)(ws + 302121984ULL);   // [T][2048] bf16, slot-major
  // total ws use: 436,339,712 bytes

  hipMemsetAsync(counts, 0, 512, stream);  // counts + cursor
  hist_k<<<T_TOK / 256, 256, 0, stream>>>(disp, counts);
  scan_k<<<1, 64, 0, stream>>>(counts, offsets);
  assign_k<<<T_TOK / 256, 256, 0, stream>>>(disp, offsets, cursor, perm);
  gather_x_k<<<T_TOK, 128, 0, stream>>>(x, perm, Xg);
  transpose_k<<<dim3(F_DIM / 64, D_DIM / 64, NE), 256, 0, stream>>>(w1, w1t, D_DIM, F_DIM);
  transpose_k<<<dim3(D_DIM / 64, F_DIM / 64, NE), 256, 0, stream>>>(w2, w2t, F_DIM, D_DIM);
  // GEMM1: [ne x 2048] = [ne x 512] * w1t^T ; gelu -> H
  gemm_k<512, 2048, true><<<dim3(16 * 8, NE), 256, 0, stream>>>(
      Xg, w1t, b1, offsets, nullptr, H, nullptr);
  // GEMM2: [ne x 512] = [ne x 2048] * w2t^T ; +b2 -> scatter fp32 out
  gemm_k<2048, 512, false><<<dim3(4 * 8, NE), 256, 0, stream>>>(
      H, w2t, b2, offsets, perm, nullptr, out);
  (void)in_sizes; (void)n_in; (void)out_size; (void)ws_size;
}

// Round 2
// 1114.900 us; speedup vs baseline: 1.0595x; 1.0595x over previous
//
#include <hip/hip_runtime.h>
#include <stdint.h>

#define T_TOK 32768
#define D_DIM 512
#define F_DIM 2048
#define NE    64

typedef __bf16 bf16_t;
typedef __bf16 bf16x8 __attribute__((ext_vector_type(8)));
typedef __bf16 bf16x4 __attribute__((ext_vector_type(4)));
typedef float  f32x4  __attribute__((ext_vector_type(4)));

// ---------- async global->LDS 16B (wave-uniform base + lane*16 rule) ----------
__device__ __forceinline__ void async_copy16(const void* g, void* l) {
  __builtin_amdgcn_global_load_lds(
      (__attribute__((address_space(1))) unsigned int*)g,
      (__attribute__((address_space(3))) unsigned int*)l, 16, 0, 0);
}

// ---------- tiny routing kernels ----------
__global__ void hist_k(const int* __restrict__ e, int* __restrict__ counts) {
  int t = blockIdx.x * 256 + threadIdx.x;
  atomicAdd(&counts[e[t]], 1);
}

__global__ void scan_k(const int* __restrict__ counts, int* __restrict__ offsets) {
  if (threadIdx.x == 0) {
    int acc = 0;
    for (int i = 0; i < NE; ++i) { offsets[i] = acc; acc += counts[i]; }
    offsets[NE] = acc;
  }
}

__global__ void assign_k(const int* __restrict__ e, const int* __restrict__ offsets,
                         int* __restrict__ cursor, int* __restrict__ perm) {
  int t = blockIdx.x * 256 + threadIdx.x;
  int ex = e[t];
  int s = atomicAdd(&cursor[ex], 1);
  perm[offsets[ex] + s] = t;
}

// gather tokens into slot order + fp32->bf16. one block (128 thr) per slot.
__global__ void gather_x_k(const float* __restrict__ x, const int* __restrict__ perm,
                           bf16_t* __restrict__ xg) {
  int s = blockIdx.x;
  int t = perm[s];
  float4 v = ((const float4*)(x + (size_t)t * D_DIM))[threadIdx.x];
  bf16x4 o = { (bf16_t)v.x, (bf16_t)v.y, (bf16_t)v.z, (bf16_t)v.w };
  *(bf16x4*)(xg + (size_t)s * D_DIM + threadIdx.x * 4) = o;
}

// ---------- vectorized transpose+convert: in [E][R][C] f32 -> out [E][C][R] bf16 ----
// 64x64 tile / 256 threads. 16B/lane on both global sides.
// LDS: fp32, row stride 68, 16B-chunk XOR swizzle keyed on (r + (r>>3)) & 15.
__global__ __launch_bounds__(256, 4)
void transpose_k(const float* __restrict__ in, bf16_t* __restrict__ out,
                 int R, int C) {
  __shared__ float tile[64 * 68];
  const int e = blockIdx.z;
  const int r0 = blockIdx.y * 64, c0 = blockIdx.x * 64;
  const float* inp = in + (size_t)e * R * C + (size_t)r0 * C + c0;
  bf16_t* outp = out + (size_t)e * C * R + (size_t)c0 * R + r0;
  const int t = threadIdx.x;
  const int c4 = t & 15;
  const int rl = t >> 4;
  #pragma unroll
  for (int pass = 0; pass < 4; ++pass) {
    int r = pass * 16 + rl;
    float4 v = *(const float4*)(inp + (size_t)r * C + c4 * 4);
    int key = (r + (r >> 3)) & 15;
    *(float4*)&tile[r * 68 + (c4 ^ key) * 4] = v;
  }
  __syncthreads();
  #pragma unroll
  for (int pass = 0; pass < 2; ++pass) {
    int task = pass * 256 + t;
    int c = task >> 3;       // 0..63
    int r8 = task & 7;       // 0..7
    bf16_t o[8];
    #pragma unroll
    for (int i = 0; i < 8; ++i) {
      int r = r8 * 8 + i;
      int key = (r + (r >> 3)) & 15;
      int phys = (c >> 2) ^ key;
      o[i] = (bf16_t)tile[r * 68 + phys * 4 + (c & 3)];
    }
    *(bf16x8*)(outp + (size_t)c * R + r8 * 8) = *(bf16x8*)o;
  }
}

// ---------- grouped GEMM: C[m][n] = sum_k A[slot][k] * Bt[e][n][k] ----------
template<int KDIM, int NDIM, bool IS_G1>
__global__ __launch_bounds__(256, 4)
void gemm_k(const bf16_t* __restrict__ A, const bf16_t* __restrict__ Bt,
            const float* __restrict__ bias, const int* __restrict__ offsets,
            const int* __restrict__ perm, bf16_t* __restrict__ Hout,
            float* __restrict__ Yout)
{
  const int e = blockIdx.y;
  const int row_base = offsets[e];
  const int ne = offsets[e + 1] - row_base;
  const int mt = blockIdx.x & 7;
  const int nt = blockIdx.x >> 3;
  const int m0 = mt << 7;
  if (m0 >= ne) return;
  const int n0 = nt << 7;
  const int mlen = min(128, ne - m0);

  __shared__ bf16_t As[128 * 64];
  __shared__ bf16_t Bs[128 * 64];

  const int tid = threadIdx.x;
  const int lane = tid & 63;
  const int wave = tid >> 6;
  const int wm = (wave >> 1) << 6;
  const int wn = (wave & 1) << 6;
  const int l15 = lane & 15;
  const int quad = lane >> 4;

  f32x4 acc[4][4] = {};

  const bf16_t* Bexp = Bt + ((size_t)e * NDIM + n0) * KDIM;

  const bf16_t* asrc[4];
  const bf16_t* bsrc[4];
  int lchunk[4];
  #pragma unroll
  for (int p = 0; p < 4; ++p) {
    int c = tid + p * 256;
    int r = c >> 3;
    int cc = c & 7;
    int gc = cc ^ (r & 7);
    int garow = row_base + m0 + r;
    garow = garow < T_TOK ? garow : (T_TOK - 1);   // clamp: padded rows read valid mem, never stored
    asrc[p] = A + (size_t)garow * KDIM + gc * 8;
    bsrc[p] = Bexp + (size_t)r * KDIM + gc * 8;
    lchunk[p] = c;
  }

  for (int kt = 0; kt < KDIM / 64; ++kt) {
    __syncthreads();
    const int k0 = kt * 64;
    #pragma unroll
    for (int p = 0; p < 4; ++p) {
      async_copy16(asrc[p] + k0, &As[lchunk[p] * 8]);
      async_copy16(bsrc[p] + k0, &Bs[lchunk[p] * 8]);
    }
    __syncthreads();
    #pragma unroll
    for (int ks = 0; ks < 2; ++ks) {
      bf16x8 af[4], bfr[4];
      #pragma unroll
      for (int i = 0; i < 4; ++i) {
        int ra = wm + i * 16 + l15;
        int pa = ((ks << 2) + quad) ^ (ra & 7);
        af[i] = *(const bf16x8*)&As[ra * 64 + pa * 8];
        int rb = wn + i * 16 + l15;
        int pb = ((ks << 2) + quad) ^ (rb & 7);
        bfr[i] = *(const bf16x8*)&Bs[rb * 64 + pb * 8];
      }
      #pragma unroll
      for (int i = 0; i < 4; ++i)
        #pragma unroll
        for (int j = 0; j < 4; ++j)
          acc[i][j] = __builtin_amdgcn_mfma_f32_16x16x32_bf16(af[i], bfr[j], acc[i][j], 0, 0, 0);
    }
  }

  // epilogue: C/D layout col=lane&15, row=quad*4+reg
  #pragma unroll
  for (int i = 0; i < 4; ++i) {
    #pragma unroll
    for (int rr = 0; rr < 4; ++rr) {
      int m = wm + i * 16 + quad * 4 + rr;
      if (m < mlen) {
        int sg = row_base + m0 + m;
        #pragma unroll
        for (int j = 0; j < 4; ++j) {
          int col = n0 + wn + j * 16 + l15;
          float v = acc[i][j][rr] + bias[e * NDIM + col];
          if (IS_G1) {
            // tanh-approx GELU via hw exp2: ~3e-4 abs err in gelu, negligible after GEMM2
            float z = v * (2.3022041f + 0.1029434f * v * v);   // = 2*log2(e)*0.7978845*(v+0.044715 v^3)
            float g = v - v * __builtin_amdgcn_rcpf(1.0f + __builtin_amdgcn_exp2f(z));
            Hout[(size_t)sg * F_DIM + col] = (bf16_t)g;
          } else {
            int t = perm[sg];
            Yout[(size_t)t * D_DIM + col] = v;
          }
        }
      }
    }
  }
}

extern "C" void kernel_launch(void* const* d_in, const int* in_sizes, int n_in,
                              void* d_out, int out_size, void* d_ws, size_t ws_size,
                              hipStream_t stream) {
  const float* x   = (const float*)d_in[0];
  const int* disp  = (const int*)d_in[1];
  const float* w1  = (const float*)d_in[2];
  const float* b1  = (const float*)d_in[3];
  const float* w2  = (const float*)d_in[4];
  const float* b2  = (const float*)d_in[5];
  float* out = (float*)d_out;

  char* ws = (char*)d_ws;
  int* counts  = (int*)(ws + 0);      // 64 ints
  int* cursor  = (int*)(ws + 256);    // 64 ints
  int* offsets = (int*)(ws + 512);    // 65 ints
  int* perm    = (int*)(ws + 1024);   // 32768 ints
  bf16_t* Xg  = (bf16_t*)(ws + 132096ULL);      // [T][512] bf16, slot-major
  bf16_t* w1t = (bf16_t*)(ws + 33686528ULL);    // [E][2048][512] bf16
  bf16_t* w2t = (bf16_t*)(ws + 167904256ULL);   // [E][512][2048] bf16
  bf16_t* H   = (bf16_t*)(ws + 302121984ULL);   // [T][2048] bf16, slot-major
  // total ws use: 436,339,712 bytes

  hipMemsetAsync(counts, 0, 512, stream);  // counts + cursor
  hist_k<<<T_TOK / 256, 256, 0, stream>>>(disp, counts);
  scan_k<<<1, 64, 0, stream>>>(counts, offsets);
  assign_k<<<T_TOK / 256, 256, 0, stream>>>(disp, offsets, cursor, perm);
  gather_x_k<<<T_TOK, 128, 0, stream>>>(x, perm, Xg);
  transpose_k<<<dim3(F_DIM / 64, D_DIM / 64, NE), 256, 0, stream>>>(w1, w1t, D_DIM, F_DIM);
  transpose_k<<<dim3(D_DIM / 64, F_DIM / 64, NE), 256, 0, stream>>>(w2, w2t, F_DIM, D_DIM);
  // GEMM1: [ne x 2048] = [ne x 512] * w1t^T ; gelu -> H
  gemm_k<512, 2048, true><<<dim3(16 * 8, NE), 256, 0, stream>>>(
      Xg, w1t, b1, offsets, nullptr, H, nullptr);
  // GEMM2: [ne x 512] = [ne x 2048] * w2t^T ; +b2 -> scatter fp32 out
  gemm_k<2048, 512, false><<<dim3(4 * 8, NE), 256, 0, stream>>>(
      H, w2t, b2, offsets, perm, nullptr, out);
  (void)in_sizes; (void)n_in; (void)out_size; (void)ws_size;
}

// Round 3
// 961.115 us; speedup vs baseline: 1.2290x; 1.1600x over previous
//
#include <hip/hip_runtime.h>
#include <stdint.h>

#define T_TOK 32768
#define D_DIM 512
#define F_DIM 2048
#define NE    64

typedef __bf16 bf16_t;
typedef __bf16 bf16x8 __attribute__((ext_vector_type(8)));
typedef __bf16 bf16x4 __attribute__((ext_vector_type(4)));
typedef float  f32x4  __attribute__((ext_vector_type(4)));

// ---------- async global->LDS 16B (wave-uniform base + lane*16 rule) ----------
__device__ __forceinline__ void async_copy16(const void* g, void* l) {
  __builtin_amdgcn_global_load_lds(
      (__attribute__((address_space(1))) unsigned int*)g,
      (__attribute__((address_space(3))) unsigned int*)l, 16, 0, 0);
}

// ---------- tiny routing kernels ----------
__global__ void hist_k(const int* __restrict__ e, int* __restrict__ counts) {
  int t = blockIdx.x * 256 + threadIdx.x;
  atomicAdd(&counts[e[t]], 1);
}

__global__ void scan_k(const int* __restrict__ counts, int* __restrict__ offsets) {
  if (threadIdx.x == 0) {
    int acc = 0;
    for (int i = 0; i < NE; ++i) { offsets[i] = acc; acc += counts[i]; }
    offsets[NE] = acc;
  }
}

__global__ void assign_k(const int* __restrict__ e, const int* __restrict__ offsets,
                         int* __restrict__ cursor, int* __restrict__ perm) {
  int t = blockIdx.x * 256 + threadIdx.x;
  int ex = e[t];
  int s = atomicAdd(&cursor[ex], 1);
  perm[offsets[ex] + s] = t;
}

// gather tokens into slot order + fp32->bf16. one block (128 thr) per slot.
__global__ void gather_x_k(const float* __restrict__ x, const int* __restrict__ perm,
                           bf16_t* __restrict__ xg) {
  int s = blockIdx.x;
  int t = perm[s];
  float4 v = ((const float4*)(x + (size_t)t * D_DIM))[threadIdx.x];
  bf16x4 o = { (bf16_t)v.x, (bf16_t)v.y, (bf16_t)v.z, (bf16_t)v.w };
  *(bf16x4*)(xg + (size_t)s * D_DIM + threadIdx.x * 4) = o;
}

// ---------- vectorized transpose+convert: in [E][R][C] f32 -> out [E][C][R] bf16 ----
__global__ __launch_bounds__(256, 4)
void transpose_k(const float* __restrict__ in, bf16_t* __restrict__ out,
                 int R, int C) {
  __shared__ float tile[64 * 68];
  const int e = blockIdx.z;
  const int r0 = blockIdx.y * 64, c0 = blockIdx.x * 64;
  const float* inp = in + (size_t)e * R * C + (size_t)r0 * C + c0;
  bf16_t* outp = out + (size_t)e * C * R + (size_t)c0 * R + r0;
  const int t = threadIdx.x;
  const int c4 = t & 15;
  const int rl = t >> 4;
  #pragma unroll
  for (int pass = 0; pass < 4; ++pass) {
    int r = pass * 16 + rl;
    float4 v = *(const float4*)(inp + (size_t)r * C + c4 * 4);
    int key = (r + (r >> 3)) & 15;
    *(float4*)&tile[r * 68 + (c4 ^ key) * 4] = v;
  }
  __syncthreads();
  #pragma unroll
  for (int pass = 0; pass < 2; ++pass) {
    int task = pass * 256 + t;
    int c = task >> 3;       // 0..63
    int r8 = task & 7;       // 0..7
    bf16_t o[8];
    #pragma unroll
    for (int i = 0; i < 8; ++i) {
      int r = r8 * 8 + i;
      int key = (r + (r >> 3)) & 15;
      int phys = (c >> 2) ^ key;
      o[i] = (bf16_t)tile[r * 68 + phys * 4 + (c & 3)];
    }
    *(bf16x8*)(outp + (size_t)c * R + r8 * 8) = *(bf16x8*)o;
  }
}

// ---------- grouped GEMM: C[m][n] = sum_k A[slot][k] * Bt[e][n][k] ----------
// 1D grid, XCD-packed: all blocks of expert e land on XCD e&7 (bid%8 == e%8),
// so the whole per-expert working set (~4MB) lives in ONE per-XCD L2.
template<int KDIM, int NDIM, int BPE_LOG, int NT_MASK, int NT_SHIFT, bool IS_G1>
__global__ __launch_bounds__(256, 4)
void gemm_k(const bf16_t* __restrict__ A, const bf16_t* __restrict__ Bt,
            const float* __restrict__ bias, const int* __restrict__ offsets,
            const int* __restrict__ perm, bf16_t* __restrict__ Hout,
            float* __restrict__ Yout)
{
  const int bid = blockIdx.x;
  const int e = (bid & 7) + (((bid >> 3) >> BPE_LOG) << 3);
  const int inner = (bid >> 3) & ((1 << BPE_LOG) - 1);
  const int nt = inner & NT_MASK;
  const int mt = inner >> NT_SHIFT;

  const int row_base = offsets[e];
  const int ne = offsets[e + 1] - row_base;
  const int m0 = mt << 7;
  if (m0 >= ne) return;
  const int n0 = nt << 7;
  const int mlen = min(128, ne - m0);

  __shared__ bf16_t As[128 * 64];
  __shared__ bf16_t Bs[128 * 64];

  const int tid = threadIdx.x;
  const int lane = tid & 63;
  const int wave = tid >> 6;
  const int wm = (wave >> 1) << 6;
  const int wn = (wave & 1) << 6;
  const int l15 = lane & 15;
  const int quad = lane >> 4;

  f32x4 acc[4][4] = {};

  const bf16_t* Bexp = Bt + ((size_t)e * NDIM + n0) * KDIM;

  const bf16_t* asrc[4];
  const bf16_t* bsrc[4];
  int lchunk[4];
  #pragma unroll
  for (int p = 0; p < 4; ++p) {
    int c = tid + p * 256;
    int r = c >> 3;
    int cc = c & 7;
    int gc = cc ^ (r & 7);
    int garow = row_base + m0 + r;
    garow = garow < T_TOK ? garow : (T_TOK - 1);   // clamp: padded rows read valid mem, never stored
    asrc[p] = A + (size_t)garow * KDIM + gc * 8;
    bsrc[p] = Bexp + (size_t)r * KDIM + gc * 8;
    lchunk[p] = c;
  }

  for (int kt = 0; kt < KDIM / 64; ++kt) {
    __syncthreads();
    const int k0 = kt * 64;
    #pragma unroll
    for (int p = 0; p < 4; ++p) {
      async_copy16(asrc[p] + k0, &As[lchunk[p] * 8]);
      async_copy16(bsrc[p] + k0, &Bs[lchunk[p] * 8]);
    }
    __syncthreads();
    #pragma unroll
    for (int ks = 0; ks < 2; ++ks) {
      bf16x8 af[4], bfr[4];
      #pragma unroll
      for (int i = 0; i < 4; ++i) {
        int ra = wm + i * 16 + l15;
        int pa = ((ks << 2) + quad) ^ (ra & 7);
        af[i] = *(const bf16x8*)&As[ra * 64 + pa * 8];
        int rb = wn + i * 16 + l15;
        int pb = ((ks << 2) + quad) ^ (rb & 7);
        bfr[i] = *(const bf16x8*)&Bs[rb * 64 + pb * 8];
      }
      #pragma unroll
      for (int i = 0; i < 4; ++i)
        #pragma unroll
        for (int j = 0; j < 4; ++j)
          acc[i][j] = __builtin_amdgcn_mfma_f32_16x16x32_bf16(af[i], bfr[j], acc[i][j], 0, 0, 0);
    }
  }

  // epilogue: C/D layout col=lane&15, row=quad*4+reg
  #pragma unroll
  for (int i = 0; i < 4; ++i) {
    #pragma unroll
    for (int rr = 0; rr < 4; ++rr) {
      int m = wm + i * 16 + quad * 4 + rr;
      if (m < mlen) {
        int sg = row_base + m0 + m;
        #pragma unroll
        for (int j = 0; j < 4; ++j) {
          int col = n0 + wn + j * 16 + l15;
          float v = acc[i][j][rr] + bias[e * NDIM + col];
          if (IS_G1) {
            // tanh-approx GELU via hw exp2: ~3e-4 abs err in gelu, negligible after GEMM2
            float z = v * (2.3022041f + 0.1029434f * v * v);
            float g = v - v * __builtin_amdgcn_rcpf(1.0f + __builtin_amdgcn_exp2f(z));
            Hout[(size_t)sg * F_DIM + col] = (bf16_t)g;
          } else {
            int t = perm[sg];
            Yout[(size_t)t * D_DIM + col] = v;
          }
        }
      }
    }
  }
}

extern "C" void kernel_launch(void* const* d_in, const int* in_sizes, int n_in,
                              void* d_out, int out_size, void* d_ws, size_t ws_size,
                              hipStream_t stream) {
  const float* x   = (const float*)d_in[0];
  const int* disp  = (const int*)d_in[1];
  const float* w1  = (const float*)d_in[2];
  const float* b1  = (const float*)d_in[3];
  const float* w2  = (const float*)d_in[4];
  const float* b2  = (const float*)d_in[5];
  float* out = (float*)d_out;

  char* ws = (char*)d_ws;
  int* counts  = (int*)(ws + 0);      // 64 ints
  int* cursor  = (int*)(ws + 256);    // 64 ints
  int* offsets = (int*)(ws + 512);    // 65 ints
  int* perm    = (int*)(ws + 1024);   // 32768 ints
  bf16_t* Xg  = (bf16_t*)(ws + 132096ULL);      // [T][512] bf16, slot-major
  bf16_t* w1t = (bf16_t*)(ws + 33686528ULL);    // [E][2048][512] bf16
  bf16_t* w2t = (bf16_t*)(ws + 167904256ULL);   // [E][512][2048] bf16
  bf16_t* H   = (bf16_t*)(ws + 302121984ULL);   // [T][2048] bf16, slot-major
  // total ws use: 436,339,712 bytes

  hipMemsetAsync(counts, 0, 512, stream);  // counts + cursor
  hist_k<<<T_TOK / 256, 256, 0, stream>>>(disp, counts);
  scan_k<<<1, 64, 0, stream>>>(disp ? counts : counts, offsets);
  assign_k<<<T_TOK / 256, 256, 0, stream>>>(disp, offsets, cursor, perm);
  gather_x_k<<<T_TOK, 128, 0, stream>>>(x, perm, Xg);
  transpose_k<<<dim3(F_DIM / 64, D_DIM / 64, NE), 256, 0, stream>>>(w1, w1t, D_DIM, F_DIM);
  transpose_k<<<dim3(D_DIM / 64, F_DIM / 64, NE), 256, 0, stream>>>(w2, w2t, F_DIM, D_DIM);
  // GEMM1: [ne x 2048] = [ne x 512] * w1t^T ; gelu -> H
  // 128 blocks/expert (16 nt x 8 mt), expert->XCD packed
  gemm_k<512, 2048, 7, 15, 4, true><<<NE * 128, 256, 0, stream>>>(
      Xg, w1t, b1, offsets, nullptr, H, nullptr);
  // GEMM2: [ne x 512] = [ne x 2048] * w2t^T ; +b2 -> scatter fp32 out
  // 32 blocks/expert (4 nt x 8 mt), expert->XCD packed
  gemm_k<2048, 512, 5, 3, 2, false><<<NE * 32, 256, 0, stream>>>(
      H, w2t, b2, offsets, perm, nullptr, out);
  (void)in_sizes; (void)n_in; (void)out_size; (void)ws_size;
}